// Round 6
// baseline (470.564 us; speedup 1.0000x reference)
//
#include <hip/hip_runtime.h>

#define BB 512
#define TT 200
#define VV 2048
#define EE 20
#define HH 100
#define G4 400   // 4*H
#define II 64
#define AA 32

typedef _Float16 half8 __attribute__((ext_vector_type(8)));
typedef float    f32x4 __attribute__((ext_vector_type(4)));
typedef float    vf2   __attribute__((ext_vector_type(2)));

#define NCHUNK 64          // K chunks of 32
// ---------------- workspace layout (4B units) ----------------
// [0..1023]            off[513] + pad
// [1024..1024+32767]   Bfrag: 65536 fp16 (64 chunks x 2 etiles x 64 lanes x 8)
// [33792.. ]           emb[512][200][20] fp32
#define WS_BF_OFF  1024
#define WS_EMB_OFF (1024 + 32768)

// ---------------- Kernel 0: prefix-sum of lengths + B-fragment pack ----------------
__global__ __launch_bounds__(512) void k0_prep(
    const int* __restrict__ lengths, const float* __restrict__ W_emb,
    int* __restrict__ off, _Float16* __restrict__ Bfrag)
{
    if (blockIdx.x == 0) {
        __shared__ int s[BB];
        int tid = threadIdx.x;
        s[tid] = lengths[tid];
        __syncthreads();
        for (int d = 1; d < BB; d <<= 1) {
            int v = (tid >= d) ? s[tid - d] : 0;
            __syncthreads();
            if (tid >= d) s[tid] += v;
            __syncthreads();
        }
        off[tid + 1] = s[tid];
        if (tid == 0) off[0] = 0;
    } else {
        int F = (blockIdx.x - 1) * 512 + threadIdx.x;   // < 65536
        if (F < NCHUNK * 2 * 64 * 8) {
            int e = F & 7, l = (F >> 3) & 63, n = (F >> 9) & 1, c = F >> 10;
            int k = c * 32 + (l >> 4) * 8 + e;
            int col = n * 16 + (l & 15);
            float v = (col < EE) ? W_emb[(size_t)col * VV + k] : 0.f;
            Bfrag[F] = (_Float16)v;
        }
    }
}

// ---------------- Kernel 1: embedding GEMM via MFMA fp16, zero LDS (FROZEN) ----------------
__global__ __launch_bounds__(256) void k1_embed(
    const float* __restrict__ batch, const int* __restrict__ off,
    const _Float16* __restrict__ Bfrag, const float* __restrict__ b_emb,
    float* __restrict__ emb)
{
    const int Nv = off[BB];
    if (blockIdx.x * 64 >= Nv) return;

    const int lane  = threadIdx.x & 63;
    const int wid   = threadIdx.x >> 6;
    const int rbase = blockIdx.x * 64 + wid * 16;

    int lrow = rbase + (lane & 15);
    int lr = (lrow < Nv) ? lrow : (Nv - 1);
    int lo = 0, hi = BB;
    while (lo + 1 < hi) {
        int mid = (lo + hi) >> 1;
        if (off[mid] <= lr) lo = mid; else hi = mid;
    }
    const int lroff = lo * TT + (lr - off[lo]);   // (b*TT + t) for this row

    const float* __restrict__ aptr = batch + (size_t)lroff * VV + ((lane >> 4) * 8);
    const half8* __restrict__ bptr = reinterpret_cast<const half8*>(Bfrag) + lane;

    f32x4 acc0 = {0.f, 0.f, 0.f, 0.f};
    f32x4 acc1 = {0.f, 0.f, 0.f, 0.f};

#pragma unroll 4
    for (int c = 0; c < NCHUNK; ++c) {
        float4 a0 = *reinterpret_cast<const float4*>(aptr + c * 32);
        float4 a1 = *reinterpret_cast<const float4*>(aptr + c * 32 + 4);
        half8 b0 = bptr[(c * 2 + 0) * 64];
        half8 b1 = bptr[(c * 2 + 1) * 64];
        half8 av;
        av[0] = (_Float16)a0.x; av[1] = (_Float16)a0.y;
        av[2] = (_Float16)a0.z; av[3] = (_Float16)a0.w;
        av[4] = (_Float16)a1.x; av[5] = (_Float16)a1.y;
        av[6] = (_Float16)a1.z; av[7] = (_Float16)a1.w;
        acc0 = __builtin_amdgcn_mfma_f32_16x16x32_f16(av, b0, acc0, 0, 0, 0);
        acc1 = __builtin_amdgcn_mfma_f32_16x16x32_f16(av, b1, acc1, 0, 0, 0);
    }

    const int col0 = lane & 15;
    const float bias0 = b_emb[col0];
    const float bias1 = (col0 < 4) ? b_emb[16 + col0] : 0.f;
#pragma unroll
    for (int r = 0; r < 4; ++r) {
        int s = (lane >> 4) * 4 + r;
        int srow = rbase + s;
        int sroff = __shfl(lroff, s, 64);
        if (srow < Nv) {
            emb[(size_t)sroff * EE + col0] = acc0[r] + bias0;
            if (col0 < 4)
                emb[(size_t)sroff * EE + 16 + col0] = acc1[r] + bias1;
        }
    }
}

// ---------------- Kernel 2: LSTM scan, segment-shared reads + DPP allreduce ----------------
// 256 blocks x 448 threads. Gate thread tid<400: rg=tid>>3, ks=tid&7.
// Owns 8 rows {100g + 2rg + d : g 0..3, d 0..1} x 16-slot segment ks of the
// padded concat [x(20); h(100); 0(8)] -> 128 pk-FMA/step. 8-lane DPP butterfly
// (xor1, xor2, half_mirror) allreduces the 8 segments; lanes q<4 update cells.
// Zero VMEM in the loop; 1 barrier/step.
__device__ __forceinline__ float fast_sig(float x) { return 1.f / (1.f + __expf(-x)); }
__device__ __forceinline__ float fast_tanh(float x) {
    x = fminf(fmaxf(x, -15.f), 15.f);
    float e = __expf(2.f * x);
    return (e - 1.f) / (e + 1.f);
}
template<int CTRL>
__device__ __forceinline__ float dpp_add(float v) {
    int p = __builtin_amdgcn_update_dpp(0, __builtin_bit_cast(int, v), CTRL, 0xF, 0xF, true);
    return v + __builtin_bit_cast(float, p);
}
#define XSTR 20   // kseg stride (floats): 8 seg bases cover all 32 banks, 16B aligned

__global__ __launch_bounds__(448) void k2_lstm(
    const float* __restrict__ emb, const int* __restrict__ lengths,
    const float* __restrict__ W_ih, const float* __restrict__ W_hh,
    const float* __restrict__ b_ih, const float* __restrict__ b_hh,
    const float* __restrict__ W1, const float* __restrict__ b1,
    const float* __restrict__ W2, const float* __restrict__ b2,
    const float* __restrict__ h0, const float* __restrict__ c0,
    float* __restrict__ out)
{
    __shared__ float emb_lds[2][TT][EE];       // 32000 B
    __shared__ float xh2[2][2][8][XSTR];       // 2560 B  [buf][batch][kseg][slot]
    __shared__ float hfin[2][HH];
    __shared__ float inter[2][II];

    const int tid = threadIdx.x;
    const int b0  = blockIdx.x * 2;
    const int len0 = lengths[b0];
    const int len1 = lengths[b0 + 1];
    const int tmax = (len0 > len1) ? len0 : len1;

    const int rg = tid >> 3, ks = tid & 7, q = tid & 7;

    // stage emb for both batches into LDS (only VMEM reads besides weights)
    {
        const float4* srcp = reinterpret_cast<const float4*>(emb + (size_t)b0 * TT * EE);
        float4* dst = reinterpret_cast<float4*>(&emb_lds[0][0][0]);
        for (int i = tid; i < 2 * TT * EE / 4; i += 448) dst[i] = srcp[i];
    }
    // zero xh buffers (pads stay zero forever)
    for (int i = tid; i < 2 * 2 * 8 * XSTR; i += 448) (&xh2[0][0][0][0])[i] = 0.f;

    // weights: w8[g][d][p] = slots (16ks+2p, 16ks+2p+1) of row 100g+2rg+d
    vf2 w8[4][2][8];
    float bias[4][2];
    float c_reg = 0.f;
    int lenq = 0;
    if (tid < G4) {
#pragma unroll
        for (int g = 0; g < 4; ++g)
#pragma unroll
            for (int d = 0; d < 2; ++d) {
                const int r = 100 * g + 2 * rg + d;
#pragma unroll
                for (int p = 0; p < 8; ++p) {
                    int s0 = 16 * ks + 2 * p;
                    float v0, v1;
                    v0 = (s0 < EE) ? W_ih[r * EE + s0]
                       : (s0 < EE + HH) ? W_hh[r * HH + s0 - EE] : 0.f;
                    int s1 = s0 + 1;
                    v1 = (s1 < EE) ? W_ih[r * EE + s1]
                       : (s1 < EE + HH) ? W_hh[r * HH + s1 - EE] : 0.f;
                    w8[g][d][p].x = v0; w8[g][d][p].y = v1;
                }
                bias[g][d] = b_ih[r] + b_hh[r];
            }
        if (q < 4) {
            const int d = q & 1, bq = q >> 1;
            c_reg = c0[(size_t)(b0 + bq) * HH + 2 * rg + d];
            lenq = bq ? len1 : len0;
        }
    }
    __syncthreads();   // emb_lds + zeros ready

    // init buf0: h0 (slots 20+j) and x_0 (slots 0..19)
    if (tid < G4) {
        if (q < 4) {
            const int d = q & 1, bq = q >> 1;
            const int s = EE + 2 * rg + d;
            xh2[0][bq][s >> 4][s & 15] = h0[(size_t)(b0 + bq) * HH + 2 * rg + d];
        }
    } else if (tid < G4 + 2 * EE) {
        const int wl = tid - G4, bw = wl / EE, e = wl - bw * EE;
        xh2[0][bw][e >> 4][e & 15] = emb_lds[bw][0][e];
    }
    __syncthreads();

#pragma unroll 1
    for (int t = 0; t < tmax; ++t) {
        const int cur = t & 1, nxt = cur ^ 1;
        if (tid < G4) {
            // read this thread's 16-slot segment for both batches
            const float* xb0 = &xh2[cur][0][ks][0];
            const float* xb1 = &xh2[cur][1][ks][0];
            vf2 acc[4][2][2];   // [g][d][batch]
#pragma unroll
            for (int g = 0; g < 4; ++g)
#pragma unroll
                for (int d = 0; d < 2; ++d) {
                    acc[g][d][0].x = 0.f; acc[g][d][0].y = 0.f;
                    acc[g][d][1].x = 0.f; acc[g][d][1].y = 0.f;
                }
#pragma unroll
            for (int m = 0; m < 4; ++m) {
                float4 x0 = *reinterpret_cast<const float4*>(xb0 + 4 * m);
                float4 x1 = *reinterpret_cast<const float4*>(xb1 + 4 * m);
                vf2 xl0, xh0, xl1, xh1;
                xl0.x = x0.x; xl0.y = x0.y;  xh0.x = x0.z; xh0.y = x0.w;
                xl1.x = x1.x; xl1.y = x1.y;  xh1.x = x1.z; xh1.y = x1.w;
#pragma unroll
                for (int g = 0; g < 4; ++g)
#pragma unroll
                    for (int d = 0; d < 2; ++d) {
                        acc[g][d][0] = __builtin_elementwise_fma(w8[g][d][2*m],   xl0, acc[g][d][0]);
                        acc[g][d][0] = __builtin_elementwise_fma(w8[g][d][2*m+1], xh0, acc[g][d][0]);
                        acc[g][d][1] = __builtin_elementwise_fma(w8[g][d][2*m],   xl1, acc[g][d][1]);
                        acc[g][d][1] = __builtin_elementwise_fma(w8[g][d][2*m+1], xh1, acc[g][d][1]);
                    }
            }
            // horizontal + 8-lane butterfly allreduce (xor1, xor2, half-mirror)
            float s16[4][2][2];
#pragma unroll
            for (int g = 0; g < 4; ++g)
#pragma unroll
                for (int d = 0; d < 2; ++d)
#pragma unroll
                    for (int bb = 0; bb < 2; ++bb) {
                        float v = acc[g][d][bb].x + acc[g][d][bb].y;
                        v = dpp_add<0xB1>(v);    // quad xor1
                        v = dpp_add<0x4E>(v);    // quad xor2
                        v = dpp_add<0x141>(v);   // row_half_mirror: xor across quads
                        s16[g][d][bb] = v;
                    }
            if (q < 4) {
                const int d = q & 1, bq = q >> 1;
                const int j = 2 * rg + d;
                float gi = s16[0][d][bq] + bias[0][d];
                float gf = s16[1][d][bq] + bias[1][d];
                float gg = s16[2][d][bq] + bias[2][d];
                float go = s16[3][d][bq] + bias[3][d];
                c_reg = fast_sig(gf) * c_reg + fast_sig(gi) * fast_tanh(gg);
                float hv = fast_sig(go) * fast_tanh(c_reg);
                const int s = EE + j;
                xh2[nxt][bq][s >> 4][s & 15] = hv;
                if (t == lenq - 1) hfin[bq][j] = hv;
            }
        } else if (tid < G4 + 2 * EE) {
            const int wl = tid - G4, bw = wl / EE, e = wl - bw * EE;
            if (t + 1 < tmax) xh2[nxt][bw][e >> 4][e & 15] = emb_lds[bw][t + 1][e];
        }
        __syncthreads();
    }

    // fused MLP
    if (tid < 2 * II) {
        int bb = tid >> 6, i = tid & 63;
        float a = b1[i];
        const float* w1r = W1 + i * HH;
#pragma unroll
        for (int k = 0; k < HH; k += 4) {
            a += w1r[k] * hfin[bb][k] + w1r[k+1] * hfin[bb][k+1]
               + w1r[k+2] * hfin[bb][k+2] + w1r[k+3] * hfin[bb][k+3];
        }
        inter[bb][i] = fmaxf(a, 0.f);
    }
    __syncthreads();
    if (tid < 2 * AA) {
        int bb = tid >> 5, ai = tid & 31;
        float a = b2[ai];
        const float* w2r = W2 + ai * II;
#pragma unroll
        for (int k = 0; k < II; ++k) a += w2r[k] * inter[bb][k];
        out[(size_t)(b0 + bb) * AA + ai] = a;
    }
}

extern "C" void kernel_launch(void* const* d_in, const int* in_sizes, int n_in,
                              void* d_out, int out_size, void* d_ws, size_t ws_size,
                              hipStream_t stream) {
    const float* batch  = (const float*)d_in[0];
    const int*   lengths= (const int*)  d_in[1];
    const float* W_emb  = (const float*)d_in[2];
    const float* b_emb  = (const float*)d_in[3];
    const float* W_ih   = (const float*)d_in[4];
    const float* W_hh   = (const float*)d_in[5];
    const float* b_ih   = (const float*)d_in[6];
    const float* b_hh   = (const float*)d_in[7];
    const float* W1     = (const float*)d_in[8];
    const float* b1     = (const float*)d_in[9];
    const float* W2     = (const float*)d_in[10];
    const float* b2     = (const float*)d_in[11];
    const float* h0     = (const float*)d_in[12];
    const float* c0     = (const float*)d_in[13];
    float* out = (float*)d_out;

    int*       off   = (int*)d_ws;
    _Float16*  Bfrag = (_Float16*)((float*)d_ws + WS_BF_OFF);
    float*     emb   = (float*)d_ws + WS_EMB_OFF;

    k0_prep<<<1 + (NCHUNK * 2 * 64 * 8 + 511) / 512, 512, 0, stream>>>(lengths, W_emb, off, Bfrag);
    k1_embed<<<(BB * TT + 63) / 64, 256, 0, stream>>>(batch, off, Bfrag, b_emb, emb);
    k2_lstm<<<BB / 2, 448, 0, stream>>>(emb, lengths, W_ih, W_hh, b_ih, b_hh,
                                        W1, b1, W2, b2, h0, c0, out);
}

// Round 7
// 401.515 us; speedup vs baseline: 1.1720x; 1.1720x over previous
//
#include <hip/hip_runtime.h>

#define BB 512
#define TT 200
#define VV 2048
#define EE 20
#define HH 100
#define G4 400   // 4*H
#define II 64
#define AA 32

typedef _Float16 half8 __attribute__((ext_vector_type(8)));
typedef float    f32x4 __attribute__((ext_vector_type(4)));
typedef float    vf2   __attribute__((ext_vector_type(2)));

#define NCHUNK 64          // K chunks of 32
// ---------------- workspace layout (4B units) ----------------
// [0..1023]            off[513] + pad
// [1024..1024+32767]   Bfrag: 65536 fp16 (64 chunks x 2 etiles x 64 lanes x 8)
// [33792.. ]           emb[512][200][20] fp32
#define WS_BF_OFF  1024
#define WS_EMB_OFF (1024 + 32768)

// ---------------- Kernel 0: prefix-sum of lengths + B-fragment pack (FROZEN) ----------------
__global__ __launch_bounds__(512) void k0_prep(
    const int* __restrict__ lengths, const float* __restrict__ W_emb,
    int* __restrict__ off, _Float16* __restrict__ Bfrag)
{
    if (blockIdx.x == 0) {
        __shared__ int s[BB];
        int tid = threadIdx.x;
        s[tid] = lengths[tid];
        __syncthreads();
        for (int d = 1; d < BB; d <<= 1) {
            int v = (tid >= d) ? s[tid - d] : 0;
            __syncthreads();
            if (tid >= d) s[tid] += v;
            __syncthreads();
        }
        off[tid + 1] = s[tid];
        if (tid == 0) off[0] = 0;
    } else {
        int F = (blockIdx.x - 1) * 512 + threadIdx.x;   // < 65536
        if (F < NCHUNK * 2 * 64 * 8) {
            int e = F & 7, l = (F >> 3) & 63, n = (F >> 9) & 1, c = F >> 10;
            int k = c * 32 + (l >> 4) * 8 + e;
            int col = n * 16 + (l & 15);
            float v = (col < EE) ? W_emb[(size_t)col * VV + k] : 0.f;
            Bfrag[F] = (_Float16)v;
        }
    }
}

// ---------------- Kernel 1: embedding GEMM via MFMA fp16, zero LDS (FROZEN) ----------------
__global__ __launch_bounds__(256) void k1_embed(
    const float* __restrict__ batch, const int* __restrict__ off,
    const _Float16* __restrict__ Bfrag, const float* __restrict__ b_emb,
    float* __restrict__ emb)
{
    const int Nv = off[BB];
    if (blockIdx.x * 64 >= Nv) return;

    const int lane  = threadIdx.x & 63;
    const int wid   = threadIdx.x >> 6;
    const int rbase = blockIdx.x * 64 + wid * 16;

    int lrow = rbase + (lane & 15);
    int lr = (lrow < Nv) ? lrow : (Nv - 1);
    int lo = 0, hi = BB;
    while (lo + 1 < hi) {
        int mid = (lo + hi) >> 1;
        if (off[mid] <= lr) lo = mid; else hi = mid;
    }
    const int lroff = lo * TT + (lr - off[lo]);   // (b*TT + t) for this row

    const float* __restrict__ aptr = batch + (size_t)lroff * VV + ((lane >> 4) * 8);
    const half8* __restrict__ bptr = reinterpret_cast<const half8*>(Bfrag) + lane;

    f32x4 acc0 = {0.f, 0.f, 0.f, 0.f};
    f32x4 acc1 = {0.f, 0.f, 0.f, 0.f};

#pragma unroll 4
    for (int c = 0; c < NCHUNK; ++c) {
        float4 a0 = *reinterpret_cast<const float4*>(aptr + c * 32);
        float4 a1 = *reinterpret_cast<const float4*>(aptr + c * 32 + 4);
        half8 b0 = bptr[(c * 2 + 0) * 64];
        half8 b1 = bptr[(c * 2 + 1) * 64];
        half8 av;
        av[0] = (_Float16)a0.x; av[1] = (_Float16)a0.y;
        av[2] = (_Float16)a0.z; av[3] = (_Float16)a0.w;
        av[4] = (_Float16)a1.x; av[5] = (_Float16)a1.y;
        av[6] = (_Float16)a1.z; av[7] = (_Float16)a1.w;
        acc0 = __builtin_amdgcn_mfma_f32_16x16x32_f16(av, b0, acc0, 0, 0, 0);
        acc1 = __builtin_amdgcn_mfma_f32_16x16x32_f16(av, b1, acc1, 0, 0, 0);
    }

    const int col0 = lane & 15;
    const float bias0 = b_emb[col0];
    const float bias1 = (col0 < 4) ? b_emb[16 + col0] : 0.f;
#pragma unroll
    for (int r = 0; r < 4; ++r) {
        int s = (lane >> 4) * 4 + r;
        int srow = rbase + s;
        int sroff = __shfl(lroff, s, 64);
        if (srow < Nv) {
            emb[(size_t)sroff * EE + col0] = acc0[r] + bias0;
            if (col0 < 4)
                emb[(size_t)sroff * EE + 16 + col0] = acc1[r] + bias1;
        }
    }
}

// ---------------- Kernel 2: 402-config + LDS-staged emb feed (ONLY change) ----------------
__device__ __forceinline__ float fast_sig(float x) { return 1.f / (1.f + __expf(-x)); }
__device__ __forceinline__ float fast_tanh(float x) {
    x = fminf(fmaxf(x, -15.f), 15.f);
    float e = __expf(2.f * x);
    return (e - 1.f) / (e + 1.f);
}
__device__ __forceinline__ float dpp_xor1_add(float v) {
    int p = __builtin_amdgcn_update_dpp(0, __builtin_bit_cast(int, v), 0xB1, 0xF, 0xF, true);
    return v + __builtin_bit_cast(float, p);
}
__device__ __forceinline__ float dpp_xor2_add(float v) {
    int p = __builtin_amdgcn_update_dpp(0, __builtin_bit_cast(int, v), 0x4E, 0xF, 0xF, true);
    return v + __builtin_bit_cast(float, p);
}
#define QSTR 36   // quarter stride in xh buffer (floats): conflict-free across q

__global__ __launch_bounds__(448) void k2_lstm(
    const float* __restrict__ emb, const int* __restrict__ lengths,
    const float* __restrict__ W_ih, const float* __restrict__ W_hh,
    const float* __restrict__ b_ih, const float* __restrict__ b_hh,
    const float* __restrict__ W1, const float* __restrict__ b1,
    const float* __restrict__ W2, const float* __restrict__ b2,
    const float* __restrict__ h0, const float* __restrict__ c0,
    float* __restrict__ out)
{
    __shared__ float emb_lds[2][TT][EE];   // 32000 B, staged once
    __shared__ float xhbuf[2][2][160];     // [buf][batch][4 quarters x QSTR]
    __shared__ float hfin[2][HH];
    __shared__ float inter[2][II];

    const int tid = threadIdx.x;
    const int b0  = blockIdx.x * 2;
    const int len0 = lengths[b0];
    const int len1 = lengths[b0 + 1];
    const int tmax = (len0 > len1) ? len0 : len1;

    const int j = tid >> 2, q = tid & 3;

    // stage emb for both batches into LDS (removes all in-loop VMEM)
    {
        const float4* srcp = reinterpret_cast<const float4*>(emb + (size_t)b0 * TT * EE);
        float4* dst = reinterpret_cast<float4*>(&emb_lds[0][0][0]);
        for (int i = tid; i < 2 * TT * EE / 4; i += 448) dst[i] = srcp[i];
    }
    for (int i = tid; i < 2 * 2 * 160; i += 448) (&xhbuf[0][0][0])[i] = 0.f;

    vf2 w2[4][16];
    float biasv[4];
    float c_reg = 0.f;
    int lenq = 0;
    if (tid < G4) {
        const int rr[4] = { j, HH + j, 2 * HH + j, 3 * HH + j };
#pragma unroll
        for (int g = 0; g < 4; ++g) {
            const int r = rr[g];
#pragma unroll
            for (int mp = 0; mp < 16; ++mp) {
                int k = q * 32 + mp * 2;
                float2 v;
                if (k + 1 < EE)           v = *reinterpret_cast<const float2*>(&W_ih[r * EE + k]);
                else if (k + 1 < EE + HH) v = *reinterpret_cast<const float2*>(&W_hh[r * HH + k - EE]);
                else                      v = make_float2(0.f, 0.f);
                w2[g][mp].x = v.x; w2[g][mp].y = v.y;
            }
            biasv[g] = b_ih[r] + b_hh[r];
        }
        if (q < 2) c_reg = c0[(size_t)(b0 + q) * HH + j];
        lenq = (q == 0) ? len0 : len1;
    }
    __syncthreads();   // emb_lds + zeros ready

    if (tid < G4) {
        if (q < 2) {
            int i = EE + j;
            xhbuf[0][q][(i >> 5) * QSTR + (i & 31)] = h0[(size_t)(b0 + q) * HH + j];
        }
    } else if (tid < G4 + 2 * EE) {
        const int wdx = tid - G4, bw = wdx / EE, e = wdx - bw * EE;
        xhbuf[0][bw][e] = emb_lds[bw][0][e];
    }
    __syncthreads();

#pragma unroll 1
    for (int t = 0; t < tmax; ++t) {
        const int cur = t & 1, nxt = cur ^ 1;
        if (tid < G4) {
            vf2 a[4][2];
#pragma unroll
            for (int g = 0; g < 4; ++g) { a[g][0].x=0.f; a[g][0].y=0.f; a[g][1].x=0.f; a[g][1].y=0.f; }
            const float* xc = &xhbuf[cur][0][0];
#pragma unroll
            for (int m8 = 0; m8 < 8; ++m8) {
                float4 x0 = *reinterpret_cast<const float4*>(xc + q * QSTR + m8 * 4);
                float4 x1 = *reinterpret_cast<const float4*>(xc + 160 + q * QSTR + m8 * 4);
                vf2 xl0, xh0, xl1, xh1;
                xl0.x = x0.x; xl0.y = x0.y;  xh0.x = x0.z; xh0.y = x0.w;
                xl1.x = x1.x; xl1.y = x1.y;  xh1.x = x1.z; xh1.y = x1.w;
#pragma unroll
                for (int g = 0; g < 4; ++g) {
                    a[g][0] = __builtin_elementwise_fma(w2[g][2*m8],   xl0, a[g][0]);
                    a[g][0] = __builtin_elementwise_fma(w2[g][2*m8+1], xh0, a[g][0]);
                    a[g][1] = __builtin_elementwise_fma(w2[g][2*m8],   xl1, a[g][1]);
                    a[g][1] = __builtin_elementwise_fma(w2[g][2*m8+1], xh1, a[g][1]);
                }
            }
            float s_[4][2];
#pragma unroll
            for (int g = 0; g < 4; ++g) {
#pragma unroll
                for (int bb = 0; bb < 2; ++bb) {
                    float v = a[g][bb].x + a[g][bb].y;
                    v = dpp_xor1_add(v);
                    v = dpp_xor2_add(v);
                    s_[g][bb] = v;
                }
            }
            if (q < 2) {
                float gi = s_[0][q] + biasv[0];
                float gf = s_[1][q] + biasv[1];
                float gg = s_[2][q] + biasv[2];
                float go = s_[3][q] + biasv[3];
                c_reg = fast_sig(gf) * c_reg + fast_sig(gi) * fast_tanh(gg);
                float hv = fast_sig(go) * fast_tanh(c_reg);
                int ii = EE + j;
                xhbuf[nxt][q][(ii >> 5) * QSTR + (ii & 31)] = hv;
                if (t == lenq - 1) hfin[q][j] = hv;
            }
        } else if (tid < G4 + 2 * EE) {
            const int wdx = tid - G4, bw = wdx / EE, e = wdx - bw * EE;
            if (t + 1 < TT) xhbuf[nxt][bw][e] = emb_lds[bw][t + 1][e];
        }
        __syncthreads();
    }

    if (tid < 2 * II) {
        int bb = tid >> 6, i = tid & 63;
        float a = b1[i];
        const float* w1r = W1 + i * HH;
#pragma unroll
        for (int k = 0; k < HH; k += 4) {
            a += w1r[k] * hfin[bb][k] + w1r[k+1] * hfin[bb][k+1]
               + w1r[k+2] * hfin[bb][k+2] + w1r[k+3] * hfin[bb][k+3];
        }
        inter[bb][i] = fmaxf(a, 0.f);
    }
    __syncthreads();
    if (tid < 2 * AA) {
        int bb = tid >> 5, ai = tid & 31;
        float a = b2[ai];
        const float* w2r = W2 + ai * II;
#pragma unroll
        for (int k = 0; k < II; ++k) a += w2r[k] * inter[bb][k];
        out[(size_t)(b0 + bb) * AA + ai] = a;
    }
}

extern "C" void kernel_launch(void* const* d_in, const int* in_sizes, int n_in,
                              void* d_out, int out_size, void* d_ws, size_t ws_size,
                              hipStream_t stream) {
    const float* batch  = (const float*)d_in[0];
    const int*   lengths= (const int*)  d_in[1];
    const float* W_emb  = (const float*)d_in[2];
    const float* b_emb  = (const float*)d_in[3];
    const float* W_ih   = (const float*)d_in[4];
    const float* W_hh   = (const float*)d_in[5];
    const float* b_ih   = (const float*)d_in[6];
    const float* b_hh   = (const float*)d_in[7];
    const float* W1     = (const float*)d_in[8];
    const float* b1     = (const float*)d_in[9];
    const float* W2     = (const float*)d_in[10];
    const float* b2     = (const float*)d_in[11];
    const float* h0     = (const float*)d_in[12];
    const float* c0     = (const float*)d_in[13];
    float* out = (float*)d_out;

    int*       off   = (int*)d_ws;
    _Float16*  Bfrag = (_Float16*)((float*)d_ws + WS_BF_OFF);
    float*     emb   = (float*)d_ws + WS_EMB_OFF;

    k0_prep<<<1 + (NCHUNK * 2 * 64 * 8 + 511) / 512, 512, 0, stream>>>(lengths, W_emb, off, Bfrag);
    k1_embed<<<(BB * TT + 63) / 64, 256, 0, stream>>>(batch, off, Bfrag, b_emb, emb);
    k2_lstm<<<BB / 2, 448, 0, stream>>>(emb, lengths, W_ih, W_hh, b_ih, b_hh,
                                        W1, b1, W2, b2, h0, c0, out);
}